// Round 5
// baseline (212.638 us; speedup 1.0000x reference)
//
#include <hip/hip_runtime.h>
#include <math.h>

// ---------------------------------------------------------------------------
// Fused 11-layer funnel MLP, round 5: wave-specialized 6-stage pipeline.
// Weights live in each wave's VGPRs (no weight LDS, no redundant re-reads).
// Stages: w0: x+L0+L1 | w1: L2 | w2,w3: L3 | w4,w5: L4 | w6: L5 | w7: L6..L10.
// Activations flow via small ping-pong LDS edges (C-layout -> B-frag 8B
// writes, b128 frag reads). One __syncthreads per step; stage s does group
// n-s. LDS = 58 KB -> 2 blocks/CU; launch_bounds(512,4) caps VGPR at 128.
// Bias via weight pad columns + 1.0-generator rows (verified rounds 3-4).
// ---------------------------------------------------------------------------

using bf16x8 = __attribute__((ext_vector_type(8))) short;   // 8 bf16 = 4 VGPRs
using f32x4  = __attribute__((ext_vector_type(4))) float;
using u16x8  = __attribute__((ext_vector_type(8))) unsigned short;
using u32x2  = __attribute__((ext_vector_type(2))) unsigned;
using u32x4  = __attribute__((ext_vector_type(4))) unsigned;
typedef __bf16 bf16x2_t __attribute__((ext_vector_type(2)));

namespace {
constexpr int NL = 11;
constexpr int IN_[NL]  = {15, 30, 60, 90, 120, 90, 60, 30, 15, 10, 5};
constexpr int OUT_[NL] = {30, 60, 90, 120, 90, 60, 30, 15, 10, 5, 1};
constexpr int KP_[NL]  = {32, 32, 64, 96, 128, 96, 64, 32, 32, 32, 32};
constexpr int NP_[NL]  = {32, 64, 96, 128, 96, 64, 32, 16, 16, 16, 16};
// LDS layout (shorts). Edges are [2 parity][2 tiles][NKT_cons][512].
constexpr int E0 = 0;                    // x scratch: 2*512 (wave0-private)
constexpr int E1 = 1024;                 // h2 (64w):  2 * 2048
constexpr int E2 = 5120;                 // h3 (96w):  2 * 3072
constexpr int E3 = 11264;                // h4 (128w): 2 * 4096
constexpr int E4 = 19456;                // h5 (96w):  2 * 3072
constexpr int E5 = 25600;                // h6 (64w):  2 * 2048
constexpr int LDS_SHORTS = 29696;
constexpr int LDS_BYTES  = LDS_SHORTS * 2;   // 59392 -> 2 blocks/CU
constexpr int G = 32;                    // rows per pipeline group (2 tiles)
}

__device__ __forceinline__ unsigned short f2bf(float f) {
    unsigned u = __float_as_uint(f);
    u += 0x7fffu + ((u >> 16) & 1u);
    return (unsigned short)(u >> 16);
}

__device__ __forceinline__ unsigned pk2(float a, float b) {
#if __has_builtin(__builtin_amdgcn_cvt_pk_bf16_f32)
    return __builtin_bit_cast(unsigned, __builtin_amdgcn_cvt_pk_bf16_f32(a, b));
#else
    bf16x2_t c;
    c[0] = (__bf16)a;
    c[1] = (__bf16)b;
    return __builtin_bit_cast(unsigned, c);
#endif
}

__device__ __forceinline__ u32x2 packrelu(f32x4 a) {
    u32x2 p;
    p[0] = pk2(fmaxf(a[0], 0.f), fmaxf(a[1], 0.f));
    p[1] = pk2(fmaxf(a[2], 0.f), fmaxf(a[3], 0.f));
    return p;
}

// Pair C-tiles (mt even=pa, odd=pb) -> 32-wide B-frag (verified round 4).
__device__ __forceinline__ bf16x8 xform(u32x2 pa, u32x2 pb, bool sel, int sA, int sB) {
    int a0 = __shfl((int)pa[0], sA);
    int b0 = __shfl((int)pb[0], sA);
    int a1 = __shfl((int)pa[1], sA);
    int b1 = __shfl((int)pb[1], sA);
    int a2 = __shfl((int)pa[0], sB);
    int b2 = __shfl((int)pb[0], sB);
    int a3 = __shfl((int)pa[1], sB);
    int b3 = __shfl((int)pb[1], sB);
    u32x4 r;
    r[0] = (unsigned)(sel ? b0 : a0);
    r[1] = (unsigned)(sel ? b1 : a1);
    r[2] = (unsigned)(sel ? b2 : a2);
    r[3] = (unsigned)(sel ? b3 : a3);
    return __builtin_bit_cast(bf16x8, r);
}

// Single C-tile (16 rows) -> 32-wide B-frag: k<16 from tile, k=16 -> 1.0
// (bias_lo column), k=17..31 -> 0.  Same lane algebra as xform with pa==pb.
__device__ __forceinline__ bf16x8 xform16(u32x2 p, int quad, int sA16, int sB16) {
    int d0 = __shfl((int)p[0], sA16);
    int d1 = __shfl((int)p[1], sA16);
    int d2 = __shfl((int)p[0], sB16);
    int d3 = __shfl((int)p[1], sB16);
    u32x4 r;
    if (quad < 2) {
        r[0] = (unsigned)d0; r[1] = (unsigned)d1;
        r[2] = (unsigned)d2; r[3] = (unsigned)d3;
    } else {
        r[0] = (quad == 2) ? 0x00003F80u : 0u;   // 1.0 at k==16
        r[1] = 0u; r[2] = 0u; r[3] = 0u;
    }
    return __builtin_bit_cast(bf16x8, r);
}

// Stage layer L's weights (A-frag-major, bias cols + 1.0-generator rows)
// into LDS at base 0.  frag f=(mt*NKT+kt) at f*512 + quad*128 + col*8 + j.
template <int L>
__device__ __forceinline__ void stage_w(const float* __restrict__ W,
                                        const float* __restrict__ B,
                                        short* s, int tid) {
    constexpr int KP = KP_[L], NP = NP_[L], INl = IN_[L], OUTl = OUT_[L];
    constexpr int NKT = KP / 32;
    for (int idx = tid; idx < NP * KP; idx += 512) {
        const int f    = idx >> 9;
        const int t    = idx & 511;
        const int quad = t >> 7;
        const int colc = (t >> 3) & 15;
        const int j    = t & 7;
        const int mt   = f / NKT;
        const int kt   = f - mt * NKT;
        const int m    = mt * 16 + colc;
        const int k    = kt * 32 + quad * 8 + j;
        float v = 0.f;
        if (m < OUTl) {
            if (k < INl) v = W[m * INl + k];
            else if (k == INl) v = B[m];                    // bias_hi
            else if (k == INl + 1) {                        // bias_lo
                float hf = __builtin_bit_cast(float, (unsigned)f2bf(B[m]) << 16);
                v = B[m] - hf;
            }
        } else if (m == OUTl || m == OUTl + 1) {
            if (k == INl) v = 1.f;                          // 1.0-generator row
        }
        s[idx] = (short)f2bf(v);
    }
}

__device__ __forceinline__ bf16x8 ldfrag(const short* p) { return *(const bf16x8*)p; }

// C-tile (global mt) -> consumer B-frag slot in an edge tile, one 8B write.
__device__ __forceinline__ void edge_write(short* tile, int mt, int col, int quad, f32x4 a) {
    const int wb = (mt >> 1) * 512 + ((mt & 1) * 2 + (quad >> 1)) * 128 + col * 8 + (quad & 1) * 4;
    *(u32x2*)(tile + wb) = packrelu(a);
}

__device__ __forceinline__ float4 ld4(const float* p) {
    float4 t;
    __builtin_memcpy(&t, p, 16);
    return t;
}

// Two 16-row tiles of x: lane (col,quad) gets x[row=t*16+col][quad*4..+3]
// (quad 3: k=12..14 + 1.0 at k=15 = bias_hi column of L0).
__device__ __forceinline__ void fetch_x2(const float* __restrict__ x, int row0,
                                         int col, int quad, float4 (&xv)[2]) {
#pragma unroll
    for (int t = 0; t < 2; ++t) {
        const float* xr = x + (long)(row0 + t * 16 + col) * 15;
        if (quad < 3) {
            xv[t] = ld4(xr + quad * 4);
        } else {
            float4 u = ld4(xr + 11);
            xv[t] = make_float4(u.y, u.z, u.w, 1.f);
        }
    }
}

extern "C" __global__ void __launch_bounds__(512, 4)
mlp_pipe(const float* __restrict__ x,
         const float* __restrict__ W0,  const float* __restrict__ B0,
         const float* __restrict__ W1,  const float* __restrict__ B1,
         const float* __restrict__ W2,  const float* __restrict__ B2,
         const float* __restrict__ W3,  const float* __restrict__ B3,
         const float* __restrict__ W4,  const float* __restrict__ B4,
         const float* __restrict__ W5,  const float* __restrict__ B5,
         const float* __restrict__ W6,  const float* __restrict__ B6,
         const float* __restrict__ W7,  const float* __restrict__ B7,
         const float* __restrict__ W8,  const float* __restrict__ B8,
         const float* __restrict__ W9,  const float* __restrict__ B9,
         const float* __restrict__ W10, const float* __restrict__ B10,
         float* __restrict__ out, int ng) {
    extern __shared__ __align__(16) short smem[];
    const int tid  = threadIdx.x;
    const int wave = tid >> 6;
    const int lane = tid & 63;
    const int col  = lane & 15;
    const int quad = lane >> 4;
    const int fo   = quad * 128 + col * 8;
    const bool sel = quad >= 2;
    const int sA   = col + 16 * (2 * (quad & 1));
    const int sB   = sA + 16;
    const int sA16 = col + 32 * (quad & 1);
    const int sB16 = sA16 + 16;

    // ---- bootstrap: stage each layer's weights to LDS, grab frags to regs ----
    bf16x8 wreg[12];
#pragma unroll
    for (int f = 0; f < 12; ++f) wreg[f] = bf16x8{0,0,0,0,0,0,0,0};

    stage_w<0>(W0, B0, smem, tid); __syncthreads();
    if (wave == 0) { wreg[0] = ldfrag(smem + fo); wreg[1] = ldfrag(smem + 512 + fo); }
    __syncthreads();
    stage_w<1>(W1, B1, smem, tid); __syncthreads();
    if (wave == 0) {
#pragma unroll
        for (int f = 0; f < 4; ++f) wreg[2 + f] = ldfrag(smem + f * 512 + fo);
    }
    __syncthreads();
    stage_w<2>(W2, B2, smem, tid); __syncthreads();
    if (wave == 1) {
#pragma unroll
        for (int f = 0; f < 12; ++f) wreg[f] = ldfrag(smem + f * 512 + fo);
    }
    __syncthreads();
    stage_w<3>(W3, B3, smem, tid); __syncthreads();
    if (wave == 2) {
#pragma unroll
        for (int f = 0; f < 12; ++f) wreg[f] = ldfrag(smem + f * 512 + fo);
    }
    if (wave == 3) {
#pragma unroll
        for (int f = 0; f < 12; ++f) wreg[f] = ldfrag(smem + (12 + f) * 512 + fo);
    }
    __syncthreads();
    stage_w<4>(W4, B4, smem, tid); __syncthreads();
    if (wave == 4) {
#pragma unroll
        for (int f = 0; f < 12; ++f) wreg[f] = ldfrag(smem + f * 512 + fo);
    }
    if (wave == 5) {
#pragma unroll
        for (int f = 0; f < 12; ++f) wreg[f] = ldfrag(smem + (12 + f) * 512 + fo);
    }
    __syncthreads();
    stage_w<5>(W5, B5, smem, tid); __syncthreads();
    if (wave == 6) {
#pragma unroll
        for (int f = 0; f < 12; ++f) wreg[f] = ldfrag(smem + f * 512 + fo);
    }
    __syncthreads();
    stage_w<6>(W6, B6, smem, tid); __syncthreads();
    if (wave == 7) {
#pragma unroll
        for (int f = 0; f < 4; ++f) wreg[f] = ldfrag(smem + f * 512 + fo);
    }
    __syncthreads();
    stage_w<7>(W7, B7, smem, tid); __syncthreads();
    if (wave == 7) wreg[4] = ldfrag(smem + fo);
    __syncthreads();
    stage_w<8>(W8, B8, smem, tid); __syncthreads();
    if (wave == 7) wreg[5] = ldfrag(smem + fo);
    __syncthreads();
    stage_w<9>(W9, B9, smem, tid); __syncthreads();
    if (wave == 7) wreg[6] = ldfrag(smem + fo);
    __syncthreads();
    stage_w<10>(W10, B10, smem, tid); __syncthreads();
    if (wave == 7) wreg[7] = ldfrag(smem + fo);
    __syncthreads();

    const int gbase = blockIdx.x * ng;
    float4 xv[2];
    if (wave == 0 && ng > 0) fetch_x2(x, gbase * G, col, quad, xv);

    // ---- 6-stage pipeline: stage s handles group n-s; 1 barrier/step ----
    for (int n = 0; n < ng + 5; ++n) {
        if (wave == 0) {
            const int g = n;
            if (g < ng) {
                // stage x (B-frag layout + bias-col 1.0s) into private scratch
                short* sx = smem + E0;
                const int off = (quad >> 1) * 128 + col * 8 + (quad & 1) * 4;
#pragma unroll
                for (int t = 0; t < 2; ++t) {
                    u32x2 o;
                    o[0] = pk2(xv[t].x, xv[t].y);
                    o[1] = pk2(xv[t].z, xv[t].w);
                    *(u32x2*)(sx + t * 512 + off) = o;
                }
                u16x8 z = {0, 0, 0, 0, 0, 0, 0, 0};
                if (!(quad & 1)) z[0] = (unsigned short)0x3F80;   // 1.0 at k==16
                *(u16x8*)(sx + (quad >> 1) * 512 + (2 + (quad & 1)) * 128 + col * 8) = z;

                if (g + 1 < ng) fetch_x2(x, (gbase + g + 1) * G, col, quad, xv);

                short* e1p = smem + E1 + (g & 1) * 2048;
#pragma unroll
                for (int t = 0; t < 2; ++t) {
                    bf16x8 xb = ldfrag(sx + t * 512 + fo);
                    // L0 (15->30): 2 mt
                    f32x4 a0 = {0.f, 0.f, 0.f, 0.f}, a1 = {0.f, 0.f, 0.f, 0.f};
                    a0 = __builtin_amdgcn_mfma_f32_16x16x32_bf16(wreg[0], xb, a0, 0, 0, 0);
                    a1 = __builtin_amdgcn_mfma_f32_16x16x32_bf16(wreg[1], xb, a1, 0, 0, 0);
                    bf16x8 h1 = xform(packrelu(a0), packrelu(a1), sel, sA, sB);
                    // L1 (30->60): 4 mt
                    f32x4 c[4];
#pragma unroll
                    for (int mt = 0; mt < 4; ++mt) c[mt] = f32x4{0.f, 0.f, 0.f, 0.f};
#pragma unroll
                    for (int mt = 0; mt < 4; ++mt)
                        c[mt] = __builtin_amdgcn_mfma_f32_16x16x32_bf16(wreg[2 + mt], h1, c[mt], 0, 0, 0);
#pragma unroll
                    for (int mt = 0; mt < 4; ++mt)
                        edge_write(e1p + t * 1024, mt, col, quad, c[mt]);
                }
            }
        } else if (wave == 1) {
            const int g = n - 1;
            if (g >= 0 && g < ng) {
                const short* e1p = smem + E1 + (g & 1) * 2048;
                short* e2p = smem + E2 + (g & 1) * 3072;
#pragma unroll
                for (int t = 0; t < 2; ++t) {
                    bf16x8 b0 = ldfrag(e1p + t * 1024 + fo);
                    bf16x8 b1 = ldfrag(e1p + t * 1024 + 512 + fo);
                    f32x4 acc[6];
#pragma unroll
                    for (int mt = 0; mt < 6; ++mt) acc[mt] = f32x4{0.f, 0.f, 0.f, 0.f};
#pragma unroll
                    for (int mt = 0; mt < 6; ++mt)
                        acc[mt] = __builtin_amdgcn_mfma_f32_16x16x32_bf16(wreg[mt * 2], b0, acc[mt], 0, 0, 0);
#pragma unroll
                    for (int mt = 0; mt < 6; ++mt)
                        acc[mt] = __builtin_amdgcn_mfma_f32_16x16x32_bf16(wreg[mt * 2 + 1], b1, acc[mt], 0, 0, 0);
#pragma unroll
                    for (int mt = 0; mt < 6; ++mt)
                        edge_write(e2p + t * 1536, mt, col, quad, acc[mt]);
                }
            }
        } else if (wave == 2 || wave == 3) {
            const int g = n - 2;
            if (g >= 0 && g < ng) {
                const short* e2p = smem + E2 + (g & 1) * 3072;
                short* e3p = smem + E3 + (g & 1) * 4096;
                const int mo = (wave == 3) ? 4 : 0;
                f32x4 acc[4][2];
#pragma unroll
                for (int mt = 0; mt < 4; ++mt)
#pragma unroll
                    for (int t = 0; t < 2; ++t) acc[mt][t] = f32x4{0.f, 0.f, 0.f, 0.f};
#pragma unroll
                for (int kt = 0; kt < 3; ++kt) {
                    bf16x8 q0 = ldfrag(e2p + kt * 512 + fo);
                    bf16x8 q1 = ldfrag(e2p + 1536 + kt * 512 + fo);
#pragma unroll
                    for (int mt = 0; mt < 4; ++mt) {
                        acc[mt][0] = __builtin_amdgcn_mfma_f32_16x16x32_bf16(wreg[mt * 3 + kt], q0, acc[mt][0], 0, 0, 0);
                        acc[mt][1] = __builtin_amdgcn_mfma_f32_16x16x32_bf16(wreg[mt * 3 + kt], q1, acc[mt][1], 0, 0, 0);
                    }
                }
#pragma unroll
                for (int mt = 0; mt < 4; ++mt)
#pragma unroll
                    for (int t = 0; t < 2; ++t)
                        edge_write(e3p + t * 2048, mo + mt, col, quad, acc[mt][t]);
            }
        } else if (wave == 4 || wave == 5) {
            const int g = n - 3;
            if (g >= 0 && g < ng) {
                const short* e3p = smem + E3 + (g & 1) * 4096;
                short* e4p = smem + E4 + (g & 1) * 3072;
                const int mo = (wave == 5) ? 3 : 0;
                f32x4 acc[3][2];
#pragma unroll
                for (int mt = 0; mt < 3; ++mt)
#pragma unroll
                    for (int t = 0; t < 2; ++t) acc[mt][t] = f32x4{0.f, 0.f, 0.f, 0.f};
#pragma unroll
                for (int kt = 0; kt < 4; ++kt) {
                    bf16x8 q0 = ldfrag(e3p + kt * 512 + fo);
                    bf16x8 q1 = ldfrag(e3p + 2048 + kt * 512 + fo);
#pragma unroll
                    for (int mt = 0; mt < 3; ++mt) {
                        const int f = mt * 4 + kt + ((wave == 5) ? 12 - 12 : 0);
                        acc[mt][0] = __builtin_amdgcn_mfma_f32_16x16x32_bf16(wreg[f], q0, acc[mt][0], 0, 0, 0);
                        acc[mt][1] = __builtin_amdgcn_mfma_f32_16x16x32_bf16(wreg[f], q1, acc[mt][1], 0, 0, 0);
                    }
                }
#pragma unroll
                for (int mt = 0; mt < 3; ++mt)
#pragma unroll
                    for (int t = 0; t < 2; ++t)
                        edge_write(e4p + t * 1536, mo + mt, col, quad, acc[mt][t]);
            }
        } else if (wave == 6) {
            const int g = n - 4;
            if (g >= 0 && g < ng) {
                const short* e4p = smem + E4 + (g & 1) * 3072;
                short* e5p = smem + E5 + (g & 1) * 2048;
                f32x4 acc[4][2];
#pragma unroll
                for (int mt = 0; mt < 4; ++mt)
#pragma unroll
                    for (int t = 0; t < 2; ++t) acc[mt][t] = f32x4{0.f, 0.f, 0.f, 0.f};
#pragma unroll
                for (int kt = 0; kt < 3; ++kt) {
                    bf16x8 q0 = ldfrag(e4p + kt * 512 + fo);
                    bf16x8 q1 = ldfrag(e4p + 1536 + kt * 512 + fo);
#pragma unroll
                    for (int mt = 0; mt < 4; ++mt) {
                        acc[mt][0] = __builtin_amdgcn_mfma_f32_16x16x32_bf16(wreg[mt * 3 + kt], q0, acc[mt][0], 0, 0, 0);
                        acc[mt][1] = __builtin_amdgcn_mfma_f32_16x16x32_bf16(wreg[mt * 3 + kt], q1, acc[mt][1], 0, 0, 0);
                    }
                }
#pragma unroll
                for (int mt = 0; mt < 4; ++mt)
#pragma unroll
                    for (int t = 0; t < 2; ++t)
                        edge_write(e5p + t * 1024, mt, col, quad, acc[mt][t]);
            }
        } else {  // wave == 7: L6..L10 + sigmoid + store
            const int g = n - 5;
            if (g >= 0 && g < ng) {
                const short* e5p = smem + E5 + (g & 1) * 2048;
#pragma unroll
                for (int t = 0; t < 2; ++t) {
                    bf16x8 b0 = ldfrag(e5p + t * 1024 + fo);
                    bf16x8 b1 = ldfrag(e5p + t * 1024 + 512 + fo);
                    // L6 (60->30)
                    f32x4 c0 = {0.f, 0.f, 0.f, 0.f}, c1 = {0.f, 0.f, 0.f, 0.f};
                    c0 = __builtin_amdgcn_mfma_f32_16x16x32_bf16(wreg[0], b0, c0, 0, 0, 0);
                    c0 = __builtin_amdgcn_mfma_f32_16x16x32_bf16(wreg[1], b1, c0, 0, 0, 0);
                    c1 = __builtin_amdgcn_mfma_f32_16x16x32_bf16(wreg[2], b0, c1, 0, 0, 0);
                    c1 = __builtin_amdgcn_mfma_f32_16x16x32_bf16(wreg[3], b1, c1, 0, 0, 0);
                    bf16x8 h7 = xform(packrelu(c0), packrelu(c1), sel, sA, sB);
                    // L7 (30->15)
                    f32x4 d = {0.f, 0.f, 0.f, 0.f};
                    d = __builtin_amdgcn_mfma_f32_16x16x32_bf16(wreg[4], h7, d, 0, 0, 0);
                    bf16x8 h8 = xform16(packrelu(d), quad, sA16, sB16);
                    // L8 (15->10)
                    f32x4 e = {0.f, 0.f, 0.f, 0.f};
                    e = __builtin_amdgcn_mfma_f32_16x16x32_bf16(wreg[5], h8, e, 0, 0, 0);
                    bf16x8 h9 = xform16(packrelu(e), quad, sA16, sB16);
                    // L9 (10->5)
                    f32x4 ff = {0.f, 0.f, 0.f, 0.f};
                    ff = __builtin_amdgcn_mfma_f32_16x16x32_bf16(wreg[6], h9, ff, 0, 0, 0);
                    bf16x8 h10 = xform16(packrelu(ff), quad, sA16, sB16);
                    // L10 (5->1) + sigmoid
                    f32x4 o = {0.f, 0.f, 0.f, 0.f};
                    o = __builtin_amdgcn_mfma_f32_16x16x32_bf16(wreg[7], h10, o, 0, 0, 0);
                    if (quad == 0)
                        out[(gbase + g) * G + t * 16 + col] = 1.f / (1.f + __expf(-o[0]));
                }
            }
        }
        __syncthreads();
    }
}

extern "C" void kernel_launch(void* const* d_in, const int* in_sizes, int n_in,
                              void* d_out, int out_size, void* d_ws, size_t ws_size,
                              hipStream_t stream) {
    (void)n_in; (void)d_ws; (void)ws_size; (void)out_size;
    const float* x = (const float*)d_in[0];
    const float* W[11];
    const float* B[11];
    for (int i = 0; i < 11; ++i) {
        W[i] = (const float*)d_in[1 + 2 * i];
        B[i] = (const float*)d_in[2 + 2 * i];
    }
    const int nrows  = in_sizes[0] / 15;
    const int blocks = 512;                       // 2 blocks/CU x 256 CUs
    const int ng     = (nrows / G) / blocks;      // 16384/512 = 32 groups/block

    hipFuncSetAttribute((const void*)mlp_pipe,
                        hipFuncAttributeMaxDynamicSharedMemorySize, LDS_BYTES);

    mlp_pipe<<<dim3(blocks), dim3(512), LDS_BYTES, stream>>>(
        x,
        W[0], B[0], W[1], B[1], W[2], B[2], W[3], B[3], W[4], B[4],
        W[5], B[5], W[6], B[6], W[7], B[7], W[8], B[8], W[9], B[9],
        W[10], B[10],
        (float*)d_out, ng);
}

// Round 7
// 208.964 us; speedup vs baseline: 1.0176x; 1.0176x over previous
//
#include <hip/hip_runtime.h>
#include <math.h>

// ---------------------------------------------------------------------------
// Fused 11-layer funnel MLP, round 7 (= round 6 + host-pass compile fix).
// 8-wave stages: w0: L0,L1 | w1: L2 | w2,w3: L3 | w4,w5: L4 | w6: L5 |
// w7: L6..L10 + sigmoid + store + x prefetch for w0.
// All weights in VGPRs. Intra-wave layer chaining uses mfma 16x16x16 whose
// B-operand layout equals the previous MFMA's C/D layout (zero relayout);
// if the _1k builtin is unavailable, an exact zero-padded 16x16x32 fallback
// is used. Cross-wave edges use the verified C-layout -> B32-frag edge_write.
// No shuffles anywhere. launch_bounds(512,2) to avoid the r5 spill.
// ---------------------------------------------------------------------------

using bf16x8 = __attribute__((ext_vector_type(8))) short;
using s16x4  = __attribute__((ext_vector_type(4))) short;
using f32x4  = __attribute__((ext_vector_type(4))) float;
using u32x2  = __attribute__((ext_vector_type(2))) unsigned;
typedef __bf16 bf16x2_t __attribute__((ext_vector_type(2)));

namespace {
constexpr int NL = 11;
constexpr int IN_[NL]  = {15, 30, 60, 90, 120, 90, 60, 30, 15, 10, 5};
constexpr int OUT_[NL] = {30, 60, 90, 120, 90, 60, 30, 15, 10, 5, 1};
constexpr int KP_[NL]  = {32, 32, 64, 96, 128, 96, 64, 32, 32, 32, 32};
constexpr int NP_[NL]  = {32, 64, 96, 128, 96, 64, 32, 16, 16, 16, 16};
// Edge buffers (shorts): [2 parity][2 tiles][NKT][512] B32-frag layout
constexpr int E1 = 0;      // h2  64w, NKT=2: 2*2048
constexpr int E2 = 4096;   // h3  96w, NKT=3: 2*3072
constexpr int E3 = 10240;  // h4 128w, NKT=4: 2*4096
constexpr int E4 = 18432;  // h5  96w, NKT=3: 2*3072
constexpr int E5 = 24576;  // h6  64w, NKT=2: 2*2048
constexpr int E6 = 28672;  // x B16-frags: [2 parity][2 tiles][256]
constexpr int LDS_SHORTS = 29696;
constexpr int LDS_BYTES  = LDS_SHORTS * 2;   // 59392 -> 2 blocks/CU
// Bootstrap staging offsets (round A / round B, pre-loop only)
constexpr int S_L0 = 0, S_L1 = 512, S_L2 = 2560, S_L3 = 8704;
constexpr int S_L7 = 20992, S_L8 = 21504, S_L9 = 21760, S_L10 = 22016;
constexpr int S_L4 = 0, S_L5 = 12288, S_L6 = 18432;
constexpr int G = 32;   // rows per group (2 tiles)
}

__device__ __forceinline__ unsigned short f2bf(float f) {
    unsigned u = __float_as_uint(f);
    u += 0x7fffu + ((u >> 16) & 1u);
    return (unsigned short)(u >> 16);
}

__device__ __forceinline__ unsigned pk2(float a, float b) {
#if defined(__HIP_DEVICE_COMPILE__) && __has_builtin(__builtin_amdgcn_cvt_pk_bf16_f32)
    return __builtin_bit_cast(unsigned, __builtin_amdgcn_cvt_pk_bf16_f32(a, b));
#else
    bf16x2_t c; c[0] = (__bf16)a; c[1] = (__bf16)b;
    return __builtin_bit_cast(unsigned, c);
#endif
}

__device__ __forceinline__ u32x2 packrelu(f32x4 a) {
    u32x2 p;
    p[0] = pk2(fmaxf(a[0], 0.f), fmaxf(a[1], 0.f));
    p[1] = pk2(fmaxf(a[2], 0.f), fmaxf(a[3], 0.f));
    return p;
}
// ReLU+pack a C-tile into the B-operand fragment of a K=16 MFMA (layouts match)
__device__ __forceinline__ s16x4 pr16(f32x4 a) {
    return __builtin_bit_cast(s16x4, packrelu(a));
}

__device__ __forceinline__ f32x4 mfma32(bf16x8 a, bf16x8 b, f32x4 c) {
    return __builtin_amdgcn_mfma_f32_16x16x32_bf16(a, b, c, 0, 0, 0);
}

__device__ __forceinline__ s16x4 lo8(bf16x8 v) { return __builtin_shufflevector(v, v, 0, 1, 2, 3); }
__device__ __forceinline__ s16x4 hi8(bf16x8 v) { return __builtin_shufflevector(v, v, 4, 5, 6, 7); }
__device__ __forceinline__ bf16x8 cat4(s16x4 a, s16x4 b) { return __builtin_shufflevector(a, b, 0, 1, 2, 3, 4, 5, 6, 7); }

// 16x16x16 bf16 MFMA. Fallback: embed K=16 into K=32 with zero-padded upper
// halves — the (quad, j<4) -> k mapping is the same bijection for A and B,
// so the result is bit-identical in products summed.
__device__ __forceinline__ f32x4 mfma16(s16x4 a, s16x4 b, f32x4 c) {
#if defined(__HIP_DEVICE_COMPILE__) && __has_builtin(__builtin_amdgcn_mfma_f32_16x16x16bf16_1k)
    return __builtin_amdgcn_mfma_f32_16x16x16bf16_1k(a, b, c, 0, 0, 0);
#else
    const s16x4 z = {0, 0, 0, 0};
    return mfma32(cat4(a, z), cat4(b, z), c);
#endif
}

__device__ __forceinline__ bf16x8 ldfrag(const short* p) { return *(const bf16x8*)p; }
__device__ __forceinline__ s16x4 ld16(const short* base, int f, int quad, int col) {
    return *(const s16x4*)(base + f * 256 + quad * 64 + col * 4);
}

// C-tile (mt) -> B32-frag slot in an edge tile (round-5 verified), one 8B write.
__device__ __forceinline__ void edge_write(short* tile, int mt, int col, int quad, f32x4 a) {
    const int wb = (mt >> 1) * 512 + ((mt & 1) * 2 + (quad >> 1)) * 128 + col * 8 + (quad & 1) * 4;
    *(u32x2*)(tile + wb) = packrelu(a);
}

// Stage a layer in K=32 A-frag-major layout (bias cols k=IN,IN+1; 1.0-gen
// rows m=OUT,OUT+1 firing on k=IN).  Used for L2..L6.
template <int L>
__device__ __forceinline__ void stage_w(const float* __restrict__ W,
                                        const float* __restrict__ B,
                                        short* dst, int tid) {
    constexpr int KP = KP_[L], NP = NP_[L], INl = IN_[L], OUTl = OUT_[L];
    constexpr int NKT = KP / 32;
    for (int idx = tid; idx < NP * KP; idx += 512) {
        const int f    = idx >> 9;
        const int t    = idx & 511;
        const int quad = t >> 7;
        const int colc = (t >> 3) & 15;
        const int j    = t & 7;
        const int mt   = f / NKT;
        const int kt   = f - mt * NKT;
        const int m    = mt * 16 + colc;
        const int k    = kt * 32 + quad * 8 + j;
        float v = 0.f;
        if (m < OUTl) {
            if (k < INl) v = W[m * INl + k];
            else if (k == INl) v = B[m];
            else if (k == INl + 1) {
                float hf = __builtin_bit_cast(float, (unsigned)f2bf(B[m]) << 16);
                v = B[m] - hf;
            }
        } else if (m == OUTl || m == OUTl + 1) {
            if (k == INl) v = 1.f;
        }
        dst[idx] = (short)f2bf(v);
    }
}

// Stage a layer in K=16 A-frag-major layout. frag f=mt*(KP16/16)+kt, elem at
// f*256 + quad*64 + col*4 + j; m=mt*16+col, k=kt*16+quad*4+j.
// Bias hi at k=IN (lo at k=IN+1 if BLO); NGEN 1.0-generator rows at k=IN.
template <int INl, int OUTl, int KP16, int NP, bool BLO, int NGEN>
__device__ __forceinline__ void stage_w16(const float* __restrict__ W,
                                          const float* __restrict__ B,
                                          short* dst, int tid) {
    for (int idx = tid; idx < NP * KP16; idx += 512) {
        const int f    = idx >> 8;
        const int t    = idx & 255;
        const int quad = t >> 6;
        const int colc = (t >> 2) & 15;
        const int j    = t & 3;
        constexpr int NKT = KP16 / 16;
        const int mt   = f / NKT;
        const int kt   = f - mt * NKT;
        const int m    = mt * 16 + colc;
        const int k    = kt * 16 + quad * 4 + j;
        float v = 0.f;
        if (m < OUTl) {
            if (k < INl) v = W[m * INl + k];
            else if (k == INl) v = B[m];
            else if (BLO && k == INl + 1) {
                float hf = __builtin_bit_cast(float, (unsigned)f2bf(B[m]) << 16);
                v = B[m] - hf;
            }
        } else if (m < OUTl + NGEN) {
            if (k == INl) v = 1.f;
        }
        dst[idx] = (short)f2bf(v);
    }
}

__device__ __forceinline__ float4 ld4(const float* p) {
    float4 t; __builtin_memcpy(&t, p, 16); return t;
}

// Lane (col,quad) fetches x[row=t*16+col][quad*4..+3] (quad3: k=12..14 + 1.0)
__device__ __forceinline__ void fetch_x2(const float* __restrict__ x, int row0,
                                         int col, int quad, float4 (&xv)[2]) {
#pragma unroll
    for (int t = 0; t < 2; ++t) {
        const float* xr = x + (long)(row0 + t * 16 + col) * 15;
        if (quad < 3) {
            xv[t] = ld4(xr + quad * 4);
        } else {
            float4 u = ld4(xr + 11);
            xv[t] = make_float4(u.y, u.z, u.w, 1.f);
        }
    }
}

extern "C" __global__ void __launch_bounds__(512, 2)
mlp_pipe(const float* __restrict__ x,
         const float* __restrict__ W0,  const float* __restrict__ B0,
         const float* __restrict__ W1,  const float* __restrict__ B1,
         const float* __restrict__ W2,  const float* __restrict__ B2,
         const float* __restrict__ W3,  const float* __restrict__ B3,
         const float* __restrict__ W4,  const float* __restrict__ B4,
         const float* __restrict__ W5,  const float* __restrict__ B5,
         const float* __restrict__ W6,  const float* __restrict__ B6,
         const float* __restrict__ W7,  const float* __restrict__ B7,
         const float* __restrict__ W8,  const float* __restrict__ B8,
         const float* __restrict__ W9,  const float* __restrict__ B9,
         const float* __restrict__ W10, const float* __restrict__ B10,
         float* __restrict__ out, int ng) {
    extern __shared__ __align__(16) short smem[];
    const int tid  = threadIdx.x;
    const int lane = tid & 63;
    const int col  = lane & 15;
    const int quad = lane >> 4;
    const int fo   = quad * 128 + col * 8;
    const int sw   = __builtin_amdgcn_readfirstlane(tid >> 6);

    bf16x8 wk[12];
#pragma unroll
    for (int f = 0; f < 12; ++f) wk[f] = bf16x8{0, 0, 0, 0, 0, 0, 0, 0};
    s16x4 t7a{0,0,0,0}, t7b{0,0,0,0}, t8{0,0,0,0}, t9{0,0,0,0}, t10{0,0,0,0};

    // ---- bootstrap round A ----
    stage_w16<15, 30, 16, 32, false, 2>(W0, B0, smem + S_L0, tid);
    stage_w16<30, 60, 32, 64, true,  2>(W1, B1, smem + S_L1, tid);
    stage_w<2>(W2, B2, smem + S_L2, tid);
    stage_w<3>(W3, B3, smem + S_L3, tid);
    stage_w16<30, 15, 32, 16, true,  1>(W7, B7, smem + S_L7, tid);
    stage_w16<15, 10, 16, 16, false, 2>(W8, B8, smem + S_L8, tid);
    stage_w16<10,  5, 16, 16, true,  2>(W9, B9, smem + S_L9, tid);
    stage_w16< 5,  1, 16, 16, true,  0>(W10, B10, smem + S_L10, tid);
    __syncthreads();
    if (sw == 0) {
        wk[0] = cat4(ld16(smem + S_L0, 0, quad, col), ld16(smem + S_L0, 1, quad, col));
#pragma unroll
        for (int m = 0; m < 4; ++m)
            wk[1 + m] = cat4(ld16(smem + S_L1, 2 * m, quad, col),
                             ld16(smem + S_L1, 2 * m + 1, quad, col));
    } else if (sw == 1) {
#pragma unroll
        for (int f = 0; f < 12; ++f) wk[f] = ldfrag(smem + S_L2 + f * 512 + fo);
    } else if (sw == 2) {
#pragma unroll
        for (int f = 0; f < 12; ++f) wk[f] = ldfrag(smem + S_L3 + f * 512 + fo);
    } else if (sw == 3) {
#pragma unroll
        for (int f = 0; f < 12; ++f) wk[f] = ldfrag(smem + S_L3 + (12 + f) * 512 + fo);
    } else if (sw == 7) {
        t7a = ld16(smem + S_L7, 0, quad, col);
        t7b = ld16(smem + S_L7, 1, quad, col);
        t8  = ld16(smem + S_L8, 0, quad, col);
        t9  = ld16(smem + S_L9, 0, quad, col);
        t10 = ld16(smem + S_L10, 0, quad, col);
    }
    __syncthreads();
    // ---- bootstrap round B ----
    stage_w<4>(W4, B4, smem + S_L4, tid);
    stage_w<5>(W5, B5, smem + S_L5, tid);
    stage_w<6>(W6, B6, smem + S_L6, tid);
    __syncthreads();
    if (sw == 4) {
#pragma unroll
        for (int f = 0; f < 12; ++f) wk[f] = ldfrag(smem + S_L4 + f * 512 + fo);
    } else if (sw == 5) {
#pragma unroll
        for (int f = 0; f < 12; ++f) wk[f] = ldfrag(smem + S_L4 + (12 + f) * 512 + fo);
    } else if (sw == 6) {
#pragma unroll
        for (int f = 0; f < 12; ++f) wk[f] = ldfrag(smem + S_L5 + f * 512 + fo);
    } else if (sw == 7) {
#pragma unroll
        for (int f = 0; f < 4; ++f) wk[f] = ldfrag(smem + S_L6 + f * 512 + fo);
    }
    __syncthreads();

    const int gbase = blockIdx.x * ng;

    // w7 primes the x edge with group 0
    if (sw == 7 && ng > 0) {
        float4 xf[2];
        fetch_x2(x, gbase * G, col, quad, xf);
#pragma unroll
        for (int t = 0; t < 2; ++t) {
            u32x2 o; o[0] = pk2(xf[t].x, xf[t].y); o[1] = pk2(xf[t].z, xf[t].w);
            *(s16x4*)(smem + E6 + t * 256 + quad * 64 + col * 4) = __builtin_bit_cast(s16x4, o);
        }
    }
    __syncthreads();

    // ---- 6-stage pipeline, one barrier per step ----
    for (int n = 0; n < ng + 5; ++n) {
        if (sw == 0) {
            const int g = n;
            if (g < ng) {
                const short* xe = smem + E6 + (g & 1) * 512;
                short* e1p = smem + E1 + (g & 1) * 2048;
#pragma unroll
                for (int t = 0; t < 2; ++t) {
                    s16x4 xb = *(const s16x4*)(xe + t * 256 + quad * 64 + col * 4);
                    f32x4 c0{0.f,0.f,0.f,0.f}, c1{0.f,0.f,0.f,0.f};
                    c0 = mfma16(lo8(wk[0]), xb, c0);
                    c1 = mfma16(hi8(wk[0]), xb, c1);
                    s16x4 h1a = pr16(c0), h1b = pr16(c1);
                    f32x4 d[4];
#pragma unroll
                    for (int mt = 0; mt < 4; ++mt) d[mt] = f32x4{0.f,0.f,0.f,0.f};
#pragma unroll
                    for (int mt = 0; mt < 4; ++mt) {
                        d[mt] = mfma16(lo8(wk[1 + mt]), h1a, d[mt]);
                        d[mt] = mfma16(hi8(wk[1 + mt]), h1b, d[mt]);
                    }
#pragma unroll
                    for (int mt = 0; mt < 4; ++mt)
                        edge_write(e1p + t * 1024, mt, col, quad, d[mt]);
                }
            }
        } else if (sw == 1) {
            const int g = n - 1;
            if (g >= 0 && g < ng) {
                const short* e1p = smem + E1 + (g & 1) * 2048;
                short* e2p = smem + E2 + (g & 1) * 3072;
#pragma unroll
                for (int t = 0; t < 2; ++t) {
                    bf16x8 b0 = ldfrag(e1p + t * 1024 + fo);
                    bf16x8 b1 = ldfrag(e1p + t * 1024 + 512 + fo);
                    f32x4 acc[6];
#pragma unroll
                    for (int mt = 0; mt < 6; ++mt) acc[mt] = f32x4{0.f,0.f,0.f,0.f};
#pragma unroll
                    for (int mt = 0; mt < 6; ++mt) {
                        acc[mt] = mfma32(wk[2 * mt], b0, acc[mt]);
                        acc[mt] = mfma32(wk[2 * mt + 1], b1, acc[mt]);
                    }
#pragma unroll
                    for (int mt = 0; mt < 6; ++mt)
                        edge_write(e2p + t * 1536, mt, col, quad, acc[mt]);
                }
            }
        } else if (sw == 2 || sw == 3) {
            const int g = n - 2;
            if (g >= 0 && g < ng) {
                const short* e2p = smem + E2 + (g & 1) * 3072;
                short* e3p = smem + E3 + (g & 1) * 4096;
                const int mo = (sw == 3) ? 4 : 0;
                f32x4 acc[4][2];
#pragma unroll
                for (int mt = 0; mt < 4; ++mt)
#pragma unroll
                    for (int t = 0; t < 2; ++t) acc[mt][t] = f32x4{0.f,0.f,0.f,0.f};
#pragma unroll
                for (int kt = 0; kt < 3; ++kt) {
                    bf16x8 q0 = ldfrag(e2p + kt * 512 + fo);
                    bf16x8 q1 = ldfrag(e2p + 1536 + kt * 512 + fo);
#pragma unroll
                    for (int mt = 0; mt < 4; ++mt) {
                        acc[mt][0] = mfma32(wk[mt * 3 + kt], q0, acc[mt][0]);
                        acc[mt][1] = mfma32(wk[mt * 3 + kt], q1, acc[mt][1]);
                    }
                }
#pragma unroll
                for (int mt = 0; mt < 4; ++mt)
#pragma unroll
                    for (int t = 0; t < 2; ++t)
                        edge_write(e3p + t * 2048, mo + mt, col, quad, acc[mt][t]);
            }
        } else if (sw == 4 || sw == 5) {
            const int g = n - 3;
            if (g >= 0 && g < ng) {
                const short* e3p = smem + E3 + (g & 1) * 4096;
                short* e4p = smem + E4 + (g & 1) * 3072;
                const int mo = (sw == 5) ? 3 : 0;
                f32x4 acc[3][2];
#pragma unroll
                for (int mt = 0; mt < 3; ++mt)
#pragma unroll
                    for (int t = 0; t < 2; ++t) acc[mt][t] = f32x4{0.f,0.f,0.f,0.f};
#pragma unroll
                for (int kt = 0; kt < 4; ++kt) {
                    bf16x8 q0 = ldfrag(e3p + kt * 512 + fo);
                    bf16x8 q1 = ldfrag(e3p + 2048 + kt * 512 + fo);
#pragma unroll
                    for (int mt = 0; mt < 3; ++mt) {
                        acc[mt][0] = mfma32(wk[mt * 4 + kt], q0, acc[mt][0]);
                        acc[mt][1] = mfma32(wk[mt * 4 + kt], q1, acc[mt][1]);
                    }
                }
#pragma unroll
                for (int mt = 0; mt < 3; ++mt)
#pragma unroll
                    for (int t = 0; t < 2; ++t)
                        edge_write(e4p + t * 1536, mo + mt, col, quad, acc[mt][t]);
            }
        } else if (sw == 6) {
            const int g = n - 4;
            if (g >= 0 && g < ng) {
                const short* e4p = smem + E4 + (g & 1) * 3072;
                short* e5p = smem + E5 + (g & 1) * 2048;
                f32x4 acc[4][2];
#pragma unroll
                for (int mt = 0; mt < 4; ++mt)
#pragma unroll
                    for (int t = 0; t < 2; ++t) acc[mt][t] = f32x4{0.f,0.f,0.f,0.f};
#pragma unroll
                for (int kt = 0; kt < 3; ++kt) {
                    bf16x8 q0 = ldfrag(e4p + kt * 512 + fo);
                    bf16x8 q1 = ldfrag(e4p + 1536 + kt * 512 + fo);
#pragma unroll
                    for (int mt = 0; mt < 4; ++mt) {
                        acc[mt][0] = mfma32(wk[mt * 3 + kt], q0, acc[mt][0]);
                        acc[mt][1] = mfma32(wk[mt * 3 + kt], q1, acc[mt][1]);
                    }
                }
#pragma unroll
                for (int mt = 0; mt < 4; ++mt)
#pragma unroll
                    for (int t = 0; t < 2; ++t)
                        edge_write(e5p + t * 1024, mt, col, quad, acc[mt][t]);
            }
        } else {   // sw == 7: L6..L10 + sigmoid + store, plus x prefetch for n+1
            const int gx = n + 1;
            float4 xf[2];
            if (gx < ng) fetch_x2(x, (gbase + gx) * G, col, quad, xf);
            const int g = n - 5;
            if (g >= 0 && g < ng) {
                const short* e5p = smem + E5 + (g & 1) * 2048;
#pragma unroll
                for (int t = 0; t < 2; ++t) {
                    bf16x8 b0 = ldfrag(e5p + t * 1024 + fo);
                    bf16x8 b1 = ldfrag(e5p + t * 1024 + 512 + fo);
                    f32x4 c0{0.f,0.f,0.f,0.f}, c1{0.f,0.f,0.f,0.f};
                    c0 = mfma32(wk[0], b0, c0);
                    c0 = mfma32(wk[1], b1, c0);
                    c1 = mfma32(wk[2], b0, c1);
                    c1 = mfma32(wk[3], b1, c1);
                    s16x4 h7a = pr16(c0), h7b = pr16(c1);
                    f32x4 d{0.f,0.f,0.f,0.f};
                    d = mfma16(t7a, h7a, d);
                    d = mfma16(t7b, h7b, d);
                    s16x4 h8 = pr16(d);
                    f32x4 e{0.f,0.f,0.f,0.f};
                    e = mfma16(t8, h8, e);
                    s16x4 h9 = pr16(e);
                    f32x4 f4{0.f,0.f,0.f,0.f};
                    f4 = mfma16(t9, h9, f4);
                    s16x4 h10 = pr16(f4);
                    f32x4 o{0.f,0.f,0.f,0.f};
                    o = mfma16(t10, h10, o);
                    if (quad == 0)
                        out[(gbase + g) * G + t * 16 + col] = 1.f / (1.f + __expf(-o[0]));
                }
            }
            if (gx < ng) {
#pragma unroll
                for (int t = 0; t < 2; ++t) {
                    u32x2 o; o[0] = pk2(xf[t].x, xf[t].y); o[1] = pk2(xf[t].z, xf[t].w);
                    *(s16x4*)(smem + E6 + (gx & 1) * 512 + t * 256 + quad * 64 + col * 4) =
                        __builtin_bit_cast(s16x4, o);
                }
            }
        }
        __syncthreads();
    }
}

extern "C" void kernel_launch(void* const* d_in, const int* in_sizes, int n_in,
                              void* d_out, int out_size, void* d_ws, size_t ws_size,
                              hipStream_t stream) {
    (void)n_in; (void)d_ws; (void)ws_size; (void)out_size;
    const float* x = (const float*)d_in[0];
    const float* W[11];
    const float* B[11];
    for (int i = 0; i < 11; ++i) {
        W[i] = (const float*)d_in[1 + 2 * i];
        B[i] = (const float*)d_in[2 + 2 * i];
    }
    const int nrows  = in_sizes[0] / 15;
    const int blocks = 512;                    // 2 blocks/CU x 256 CUs
    const int ng     = nrows / (blocks * G);   // 32 groups per block

    mlp_pipe<<<dim3(blocks), dim3(512), LDS_BYTES, stream>>>(
        x,
        W[0], B[0], W[1], B[1], W[2], B[2], W[3], B[3], W[4], B[4],
        W[5], B[5], W[6], B[6], W[7], B[7], W[8], B[8], W[9], B[9],
        W[10], B[10],
        (float*)d_out, ng);
}